// Round 4
// baseline (235.199 us; speedup 1.0000x reference)
//
#include <hip/hip_runtime.h>
#include <cmath>
#include <cstdint>

#define TSZ 1024
#define RDIV 2.5f
#define UCONST 0.83f

typedef __bf16 bf16x8 __attribute__((ext_vector_type(8)));
typedef float f32x4 __attribute__((ext_vector_type(4)));
typedef unsigned short ushortT;

__device__ __forceinline__ ushortT bf16r(float f) {
  union { float f; unsigned u; } x; x.f = f;
  unsigned r = (x.u + 0x7FFFu + ((x.u >> 16) & 1u)) >> 16;
  return (ushortT)r;
}

__device__ __forceinline__ void glds16(const void* g, void* l) {
  __builtin_amdgcn_global_load_lds(
      (const __attribute__((address_space(1))) unsigned int*)(g),
      (__attribute__((address_space(3))) unsigned int*)(l), 16, 0, 0);
}

// ---------------- fused vote + NCHW->NHWC bf16 convert ----------------
__global__ __launch_bounds__(256) void k_votecvt(const float* __restrict__ in,
                                                 const float* __restrict__ a,
                                                 const float* __restrict__ bb,
                                                 int* __restrict__ count,
                                                 ushortT* __restrict__ nb) {
  __shared__ float sb[6][8][64];   // rows y0-1..y0+4, 8 channels, 64 x
  __shared__ int hist[TSZ];
  const int t = threadIdx.x;
  for (int i = t; i < TSZ; i += 256) hist[i] = 0;
  const int bid = blockIdx.x;          // 256 = 16 n * 16 stripes
  const int n = bid >> 4, y0 = (bid & 15) << 2;
  const int x = t & 63, ry = t >> 6;   // pixel (y0+ry, x)
  const int yq = y0 + ry;
  float acc = 0.f;
  const float* base = in + (size_t)n * 524288;
  ushortT* nbrow = nb + (((size_t)(n * 64 + yq) << 6) + x) * 128;
  for (int cc = 0; cc < 16; ++cc) {
    __syncthreads();
#pragma unroll
    for (int k = 0; k < 12; ++k) {
      int i = k * 256 + t;
      int row = i >> 9;
      int c8 = (i >> 6) & 7;
      int xx = i & 63;
      int yy = y0 - 1 + row;
      float v = 0.f;
      if ((unsigned)yy < 64u) v = base[(size_t)(cc * 8 + c8) * 4096 + yy * 64 + xx];
      sb[row][c8][xx] = v;
    }
    __syncthreads();
#pragma unroll
    for (int c8 = 0; c8 < 8; ++c8) {
      const float* av = a + (cc * 8 + c8) * 9;
#pragma unroll
      for (int ky = 0; ky < 3; ++ky) {
        const float* rowp = sb[ry + ky][c8];
        float left  = (x >= 1)  ? rowp[x - 1] : 0.f;
        float mid   = rowp[x];
        float right = (x <= 62) ? rowp[x + 1] : 0.f;
        acc += left * av[ky * 3 + 0] + mid * av[ky * 3 + 1] + right * av[ky * 3 + 2];
      }
    }
    // emit NHWC bf16 for the 4 inner rows (this thread's pixel)
    {
      union { ushortT us[8]; uint4 v; } pk;
#pragma unroll
      for (int c8 = 0; c8 < 8; ++c8) pk.us[c8] = bf16r(sb[ry + 1][c8][x]);
      *reinterpret_cast<uint4*>(nbrow + cc * 8) = pk.v;
    }
  }
  {
    const float* av = a + 1152;
#pragma unroll
    for (int ky = 0; ky < 3; ++ky) {
      int yy = yq + ky - 1;
      if ((unsigned)yy >= 64u) continue;
#pragma unroll
      for (int kx = 0; kx < 3; ++kx) {
        int xx = x + kx - 1;
        if ((unsigned)xx >= 64u) continue;
        acc += 0.5f * av[ky * 3 + kx];
      }
    }
  }
  int v = (int)floorf((acc + bb[0]) / RDIV);
  int r = v % TSZ; if (r < 0) r = -r;
  atomicAdd(&hist[r], 1);
  __syncthreads();
  for (int i = t; i < TSZ; i += 256) {
    int h = hist[i];
    if (h) atomicAdd(&count[i], h);
  }
}

// ---------------- row norms -> atomicMax(max ||row||^2) ----------------
__global__ __launch_bounds__(256) void k_norm(const float* __restrict__ k,
                                              unsigned* __restrict__ scaleBits) {
  int o = blockIdx.x;
  const float* row = k + (size_t)o * 1152;
  float s = 0.f;
  for (int j = threadIdx.x; j < 1152; j += 256) { float v = row[j]; s += v * v; }
  __shared__ float red[256];
  red[threadIdx.x] = s; __syncthreads();
  for (int st = 128; st; st >>= 1) {
    if (threadIdx.x < st) red[threadIdx.x] += red[threadIdx.x + st];
    __syncthreads();
  }
  if (threadIdx.x == 0) atomicMax(scaleBits, __float_as_uint(red[0]));
}

__global__ __launch_bounds__(256) void k_hash(const float* __restrict__ k,
                                              const float* __restrict__ a,
                                              const float* __restrict__ b,
                                              const unsigned* __restrict__ scaleBits,
                                              int* __restrict__ bucket) {
  int o = blockIdx.x;
  float scale = UCONST / sqrtf(__uint_as_float(scaleBits[0]));
  const float* row = k + (size_t)o * 1152;
  float dot = 0.f, p = 0.f;
  for (int j = threadIdx.x; j < 1152; j += 256) {
    float x = row[j] * scale;
    dot += x * a[j];
    p += x * x;
  }
  __shared__ float rd[256], rp[256];
  rd[threadIdx.x] = dot; rp[threadIdx.x] = p; __syncthreads();
  for (int st = 128; st; st >>= 1) {
    if (threadIdx.x < st) { rd[threadIdx.x] += rd[threadIdx.x + st]; rp[threadIdx.x] += rp[threadIdx.x + st]; }
    __syncthreads();
  }
  if (threadIdx.x == 0) {
    float acc = rd[0];
    float pw = rp[0];
    for (int i = 0; i < 9; i++) { acc += pw * a[1152 + i]; pw = pw * pw; }
    acc += b[0];
    float h = floorf(acc / RDIV);
    int hi = (int)h;
    int r = hi % TSZ; if (r < 0) r = -r;
    bucket[o] = r;
  }
}

__global__ __launch_bounds__(1024) void k_argmax(const int* __restrict__ count,
                                                 const int* __restrict__ bucket,
                                                 int* __restrict__ maskI,
                                                 float* __restrict__ tail) {
  __shared__ int sc[1024];
  __shared__ int si[1024];
  int t = threadIdx.x;
  sc[t] = count[t]; si[t] = t; __syncthreads();
  for (int st = 512; st; st >>= 1) {
    if (t < st) {
      int c2 = sc[t + st], i2 = si[t + st];
      if (c2 > sc[t] || (c2 == sc[t] && i2 < si[t])) { sc[t] = c2; si[t] = i2; }
    }
    __syncthreads();
  }
  int idx = si[0];
  if (t == 0) tail[0] = (float)idx;
  if (t < 256) {
    int m = (bucket[t] == idx) ? 1 : 0;
    maskI[t] = m;
    tail[1 + t] = (float)m;
  }
}

// ---------------- weight prep: masked bf16, k = tap*128 + c ----------------
__global__ __launch_bounds__(256) void k_wprep(const float* __restrict__ w,
                                               const int* __restrict__ maskI,
                                               ushortT* __restrict__ wb) {
  const int o = blockIdx.x;
  const float m = maskI[o] ? 1.f : 0.f;
  const float* wr = w + (size_t)o * 1152;
  ushortT* dst = wb + (size_t)o * 1152;
  for (int j = threadIdx.x; j < 1152; j += 256) {
    int r = j >> 7, c = j & 127;
    dst[j] = bf16r(wr[c * 9 + r] * m);
  }
}

// ---------------- implicit-GEMM, counted-vmcnt pipeline ----------------
// M=65536, N=256, K=1152. BM=256 (4 rows), BN=128, BK=64. 512 thr = 8 waves
// (4M x 2N), per-wave 64x64 out. 3 LDS bufs (48KB each), staged 2 tiles
// ahead; per-tile gate = s_waitcnt vmcnt(6) + one s_barrier. LDS is
// MFMA-fragment-linear (chunk*1024 + lane*16) -> zero bank conflicts.
__global__ __launch_bounds__(512, 1) void k_gemm8(const ushortT* __restrict__ nb,
                                                  const ushortT* __restrict__ wb,
                                                  const char* __restrict__ zp,
                                                  float* __restrict__ out) {
  __shared__ __align__(16) char smem[3 * 49152];
  const int t = threadIdx.x, l = t & 63, w = t >> 6;
  const int mb = blockIdx.x, ob = blockIdx.y;
  const int n = mb >> 4, y0 = (mb & 15) << 2;
  const int o0 = ob << 7;
  const int wm = w & 3, wn = w >> 2;
  const int lr = l & 15, lq = l >> 4;
  const char* nbN = (const char*)nb + (size_t)n * 1048576;
  const char* wbC = (const char*)wb;
  const int zoff = lq << 4;

  // per-wave staging chunk descriptors: chunks c = w*6 + j, j=0..5
  // c in [0,32): A chunk (mi = c>>1, ks = c&1); c in [32,48): B (ni = (c>>1)-16)
  bool isAv[6];
  int aPx[6], aPy[6], kb[6], ldso[6];
  const char* bP[6];
#pragma unroll
  for (int j = 0; j < 6; ++j) {
    int c = w * 6 + j;
    isAv[j] = (c < 32);
    int hi = c >> 1;
    int ks = c & 1;
    kb[j] = (ks << 6) + (lq << 4);         // k-part byte offset within row
    ldso[j] = c << 10;                     // chunk byte offset within buf
    aPx[j] = ((hi & 3) << 4) + lr;         // x (pre-dx)
    aPy[j] = hi >> 2;                      // local row (pre-dy)
    int brow = o0 + ((hi - 16) << 4) + lr;
    bP[j] = wbC + (size_t)brow * 2304 + kb[j];
  }

#define STAGE_HALF(TT, JLO)                                                \
  {                                                                        \
    const int tt_ = (TT);                                                  \
    const int tap_ = tt_ >> 1;                                             \
    const int d3_ = tap_ / 3;                                              \
    const int dyv_ = d3_ - 1;                                              \
    const int dxv_ = tap_ - d3_ * 3 - 1;                                   \
    const int chb_ = (tt_ & 1) << 7;                                       \
    char* bufb_ = smem + (tt_ % 3) * 49152;                                \
    _Pragma("unroll")                                                      \
    for (int j = (JLO); j < (JLO) + 3; ++j) {                              \
      const char* src_;                                                    \
      if (isAv[j]) {                                                       \
        int yy_ = y0 + aPy[j] + dyv_;                                      \
        int xx_ = aPx[j] + dxv_;                                           \
        bool ok_ = ((unsigned)yy_ < 64u) && ((unsigned)xx_ < 64u);         \
        src_ = ok_ ? (nbN + (((yy_ << 6) + xx_) << 8) + chb_ + kb[j])      \
                   : (zp + zoff);                                          \
      } else {                                                             \
        src_ = bP[j] + tt_ * 128;                                          \
      }                                                                    \
      glds16(src_, bufb_ + ldso[j]);                                       \
    }                                                                      \
  }

  f32x4 acc[4][4] = {};

  // prologue: stage tiles 0 and 1 (6 chunks each per wave)
  STAGE_HALF(0, 0);
  STAGE_HALF(0, 3);
  STAGE_HALF(1, 0);
  STAGE_HALF(1, 3);
  asm volatile("s_waitcnt vmcnt(6)" ::: "memory");   // tile 0 landed
  __builtin_amdgcn_s_barrier();

  for (int tt = 0; tt < 18; ++tt) {
    if (tt > 0) {
      if (tt < 17) { asm volatile("s_waitcnt vmcnt(6)" ::: "memory"); }
      else         { asm volatile("s_waitcnt vmcnt(0)" ::: "memory"); }
      __builtin_amdgcn_s_barrier();
    }
    const char* bufb = smem + (tt % 3) * 49152;
#pragma unroll
    for (int ks = 0; ks < 2; ++ks) {
      if (tt < 16) {
        if (ks == 0) STAGE_HALF(tt + 2, 0)
        else         STAGE_HALF(tt + 2, 3)
      }
      bf16x8 af[4], bv[4];
#pragma unroll
      for (int mil = 0; mil < 4; ++mil)
        af[mil] = *reinterpret_cast<const bf16x8*>(
            bufb + (((((wm << 2) + mil) << 1) + ks) << 10) + (l << 4));
#pragma unroll
      for (int nil = 0; nil < 4; ++nil)
        bv[nil] = *reinterpret_cast<const bf16x8*>(
            bufb + 32768 + (((((wn << 2) + nil) << 1) + ks) << 10) + (l << 4));
#pragma unroll
      for (int mil = 0; mil < 4; ++mil)
#pragma unroll
        for (int nil = 0; nil < 4; ++nil)
          acc[mil][nil] = __builtin_amdgcn_mfma_f32_16x16x32_bf16(
              af[mil], bv[nil], acc[mil][nil], 0, 0, 0);
    }
  }

  // epilogue: C row = lq*4 + reg (x within 16-block), col = lr (o)
#pragma unroll
  for (int nil = 0; nil < 4; ++nil) {
    const int o = o0 + (wn << 6) + (nil << 4) + lr;
    float* op = out + ((size_t)((n << 8) + o) << 12) + ((y0 + wm) << 6) + (lq << 2);
#pragma unroll
    for (int mil = 0; mil < 4; ++mil)
      *reinterpret_cast<f32x4*>(op + (mil << 4)) = acc[mil][nil];
  }
#undef STAGE_HALF
}

// ---------------- fallback kernels (small-ws path, known-good) ----------------
__global__ __launch_bounds__(256) void k_vote2(const float* __restrict__ in,
                                               const float* __restrict__ a,
                                               const float* __restrict__ bb,
                                               int* __restrict__ count) {
  __shared__ float sb[6][8][64];
  __shared__ int hist[TSZ];
  const int t = threadIdx.x;
  for (int i = t; i < TSZ; i += 256) hist[i] = 0;
  const int bid = blockIdx.x;
  const int n = bid >> 4, y0 = (bid & 15) << 2;
  const int x = t & 63, ry = t >> 6;
  const int yq = y0 + ry;
  float acc = 0.f;
  const float* base = in + (size_t)n * 524288;
  for (int cc = 0; cc < 16; ++cc) {
    __syncthreads();
#pragma unroll
    for (int k = 0; k < 12; ++k) {
      int i = k * 256 + t;
      int row = i >> 9;
      int c8 = (i >> 6) & 7;
      int xx = i & 63;
      int yy = y0 - 1 + row;
      float v = 0.f;
      if ((unsigned)yy < 64u) v = base[(size_t)(cc * 8 + c8) * 4096 + yy * 64 + xx];
      sb[row][c8][xx] = v;
    }
    __syncthreads();
#pragma unroll
    for (int c8 = 0; c8 < 8; ++c8) {
      const float* av = a + (cc * 8 + c8) * 9;
#pragma unroll
      for (int ky = 0; ky < 3; ++ky) {
        const float* rowp = sb[ry + ky][c8];
        float left  = (x >= 1)  ? rowp[x - 1] : 0.f;
        float mid   = rowp[x];
        float right = (x <= 62) ? rowp[x + 1] : 0.f;
        acc += left * av[ky * 3 + 0] + mid * av[ky * 3 + 1] + right * av[ky * 3 + 2];
      }
    }
  }
  {
    const float* av = a + 1152;
#pragma unroll
    for (int ky = 0; ky < 3; ++ky) {
      int yy = yq + ky - 1;
      if ((unsigned)yy >= 64u) continue;
#pragma unroll
      for (int kx = 0; kx < 3; ++kx) {
        int xx = x + kx - 1;
        if ((unsigned)xx >= 64u) continue;
        acc += 0.5f * av[ky * 3 + kx];
      }
    }
  }
  int v = (int)floorf((acc + bb[0]) / RDIV);
  int r = v % TSZ; if (r < 0) r = -r;
  atomicAdd(&hist[r], 1);
  __syncthreads();
  for (int i = t; i < TSZ; i += 256) {
    int h = hist[i];
    if (h) atomicAdd(&count[i], h);
  }
}

__global__ __launch_bounds__(256) void k_conv(const float* __restrict__ in,
                                              const float* __restrict__ w,
                                              const int* __restrict__ maskI,
                                              float* __restrict__ out) {
  const int og = blockIdx.x, n = blockIdx.y, yt = blockIdx.z;
  const int tid = threadIdx.x;
  const int tx = tid & 63, trow = tid >> 6;
  const int y0 = yt * 4;
  const int oc0 = og * 4;
  const int m0 = maskI[oc0], m1 = maskI[oc0 + 1], m2 = maskI[oc0 + 2], m3 = maskI[oc0 + 3];
  float* op = out + ((size_t)(n * 256 + oc0)) * 4096 + (size_t)(y0 + trow) * 64 + tx;
  if (!(m0 | m1 | m2 | m3)) {
    op[0] = 0.f; op[4096] = 0.f; op[8192] = 0.f; op[12288] = 0.f;
    return;
  }
  __shared__ float tile[6 * 66];
  const float* base = in + (size_t)n * 128 * 4096;
  const float* wb = w + (size_t)oc0 * 1152;
  float a0 = 0.f, a1 = 0.f, a2 = 0.f, a3 = 0.f;
  for (int c = 0; c < 128; c++) {
    __syncthreads();
    for (int i = tid; i < 396; i += 256) {
      int r = i / 66, col = i - r * 66;
      int yy = y0 - 1 + r, xx = col - 1;
      float v = 0.f;
      if ((unsigned)yy < 64u && (unsigned)xx < 64u) v = base[(size_t)c * 4096 + yy * 64 + xx];
      tile[i] = v;
    }
    __syncthreads();
    const int ro = trow * 66 + tx;
    float t00 = tile[ro],        t01 = tile[ro + 1],   t02 = tile[ro + 2];
    float t10 = tile[ro + 66],   t11 = tile[ro + 67],  t12 = tile[ro + 68];
    float t20 = tile[ro + 132],  t21 = tile[ro + 133], t22 = tile[ro + 134];
    const float* wc = wb + c * 9;
    if (m0) { const float* q = wc;        a0 += t00*q[0]+t01*q[1]+t02*q[2]+t10*q[3]+t11*q[4]+t12*q[5]+t20*q[6]+t21*q[7]+t22*q[8]; }
    if (m1) { const float* q = wc + 1152; a1 += t00*q[0]+t01*q[1]+t02*q[2]+t10*q[3]+t11*q[4]+t12*q[5]+t20*q[6]+t21*q[7]+t22*q[8]; }
    if (m2) { const float* q = wc + 2304; a2 += t00*q[0]+t01*q[1]+t02*q[2]+t10*q[3]+t11*q[4]+t12*q[5]+t20*q[6]+t21*q[7]+t22*q[8]; }
    if (m3) { const float* q = wc + 3456; a3 += t00*q[0]+t01*q[1]+t02*q[2]+t10*q[3]+t11*q[4]+t12*q[5]+t20*q[6]+t21*q[7]+t22*q[8]; }
  }
  op[0]     = m0 ? a0 : 0.f;
  op[4096]  = m1 ? a1 : 0.f;
  op[8192]  = m2 ? a2 : 0.f;
  op[12288] = m3 ? a3 : 0.f;
}

extern "C" void kernel_launch(void* const* d_in, const int* in_sizes, int n_in,
                              void* d_out, int out_size, void* d_ws, size_t ws_size,
                              hipStream_t stream) {
  const float* in = (const float*)d_in[0];   // [16,128,64,64]
  const float* kw = (const float*)d_in[1];   // [256,128,3,3]
  const float* a  = (const float*)d_in[2];   // [1161]
  const float* b  = (const float*)d_in[3];   // [1]
  float* out = (float*)d_out;                // 16777216 + 1 + 256 floats

  char* ws = (char*)d_ws;
  const size_t NEED = 17374720ULL;

  if (ws_size >= NEED) {
    // -------- fast path --------
    ushortT* nb     = (ushortT*)(ws);                 // 16,777,216 B NHWC bf16
    ushortT* wb     = (ushortT*)(ws + 16777216);      // 589,824 B
    int* count      = (int*)(ws + 17367040);          // 4096 B
    unsigned* scB   = (unsigned*)(ws + 17371136);     // 4 B
    char* zpage     = (ws + 17371152);                // 256 B
    int* bucket     = (int*)(ws + 17371408);          // 1024 B
    int* maskI      = (int*)(ws + 17372432);          // 1024 B

    hipMemsetAsync(ws + 17367040, 0, 4368, stream);   // count + scaleBits + zpage

    k_norm<<<256, 256, 0, stream>>>(kw, scB);
    k_hash<<<256, 256, 0, stream>>>(kw, a, b, scB, bucket);
    k_votecvt<<<256, 256, 0, stream>>>(in, a, b, count, nb);
    k_argmax<<<1, 1024, 0, stream>>>(count, bucket, maskI, out + 16777216);
    k_wprep<<<256, 256, 0, stream>>>(kw, maskI, wb);

    dim3 grid(256, 2);
    k_gemm8<<<grid, 512, 0, stream>>>(nb, wb, zpage, out);
  } else {
    // -------- fallback: direct conv path --------
    int* count      = (int*)(ws);                     // 4096
    unsigned* scB   = (unsigned*)(ws + 4096);         // 4
    int* bucket     = (int*)(ws + 4160);              // 1024
    int* maskI      = (int*)(ws + 5184);              // 1024

    hipMemsetAsync(ws, 0, 4100, stream);
    k_norm<<<256, 256, 0, stream>>>(kw, scB);
    k_hash<<<256, 256, 0, stream>>>(kw, a, b, scB, bucket);
    k_vote2<<<256, 256, 0, stream>>>(in, a, b, count);
    k_argmax<<<1, 1024, 0, stream>>>(count, bucket, maskI, out + 16777216);
    dim3 grid(64, 16, 16);
    k_conv<<<grid, 256, 0, stream>>>(in, kw, maskI, out);
  }
}

// Round 5
// 178.675 us; speedup vs baseline: 1.3164x; 1.3164x over previous
//
#include <hip/hip_runtime.h>
#include <cmath>
#include <cstdint>

#define TSZ 1024
#define RDIV 2.5f
#define UCONST 0.83f

typedef __bf16 bf16x8 __attribute__((ext_vector_type(8)));
typedef float f32x4 __attribute__((ext_vector_type(4)));
typedef unsigned short ushortT;

__device__ __forceinline__ ushortT bf16r(float f) {
  union { float f; unsigned u; } x; x.f = f;
  unsigned r = (x.u + 0x7FFFu + ((x.u >> 16) & 1u)) >> 16;
  return (ushortT)r;
}

__device__ __forceinline__ void glds16(const void* g, void* l) {
  __builtin_amdgcn_global_load_lds(
      (const __attribute__((address_space(1))) unsigned int*)(g),
      (__attribute__((address_space(3))) unsigned int*)(l), 16, 0, 0);
}

// ============ k_cvtg: NCHW fp32 -> (NHWC bf16) + per-pixel 9-tap dots ============
// grid 1024 = (n, y). Block loads row y of all 128 ch, transposes via LDS,
// emits nb (coalesced 16B stores) and g[tap][n][y][x] = sum_c a[c*9+tap]*in[c,y,x].
__global__ __launch_bounds__(256) void k_cvtg(const float* __restrict__ in,
                                              const float* __restrict__ a,
                                              ushortT* __restrict__ nb,
                                              float* __restrict__ g) {
  __shared__ float tile2[64][129];       // [x][ch], stride 129 dwords
  __shared__ float gpart[4][9][64];
  const int bid = blockIdx.x;
  const int n = bid >> 6, y = bid & 63;
  const int t = threadIdx.x;

  // ---- load: f32x4 per thread, 8 iters: ch = i*16 + (t>>4), x = (t&15)*4..+3
  {
    const int chs = t >> 4, l16 = t & 15;
    const float* basep = in + ((size_t)(n * 128) << 12) + (y << 6) + (l16 << 2);
#pragma unroll
    for (int i = 0; i < 8; ++i) {
      int ch = (i << 4) + chs;
      f32x4 v = *reinterpret_cast<const f32x4*>(basep + ((size_t)ch << 12));
#pragma unroll
      for (int u = 0; u < 4; ++u) tile2[(l16 << 2) + u][ch] = v[u];
    }
  }
  __syncthreads();

  // ---- g partials: wave = ch-part (uniform -> scalar a loads), lanes = x
  {
    const int part = __builtin_amdgcn_readfirstlane(t >> 6);
    const int x = t & 63;
    float gacc[9];
#pragma unroll
    for (int tap = 0; tap < 9; ++tap) gacc[tap] = 0.f;
    const int c0 = part << 5;
#pragma unroll
    for (int i = 0; i < 32; ++i) {
      float v = tile2[x][c0 + i];
      const float* ap = a + (c0 + i) * 9;
#pragma unroll
      for (int tap = 0; tap < 9; ++tap) gacc[tap] += v * ap[tap];
    }
#pragma unroll
    for (int tap = 0; tap < 9; ++tap) gpart[part][tap][x] = gacc[tap];
  }
  __syncthreads();

  if (t < 64) {
    const int x = t;
#pragma unroll
    for (int tap = 0; tap < 9; ++tap) {
      float s = gpart[0][tap][x] + gpart[1][tap][x] + gpart[2][tap][x] + gpart[3][tap][x];
      g[tap * 65536 + (n << 12) + (y << 6) + x] = s;
    }
  }

  // ---- nb pack: thread -> pixel x2 = t>>2, 16B chunk (t&3)*8 + j*32
  {
    const int x2 = t >> 2;
    ushortT* dst = nb + (((size_t)((n << 6) + y) << 6) + x2) * 128;
#pragma unroll
    for (int j = 0; j < 4; ++j) {
      int c0 = ((t & 3) << 3) + (j << 5);
      union { ushortT us[8]; uint4 v; } pk;
#pragma unroll
      for (int u = 0; u < 8; ++u) pk.us[u] = bf16r(tile2[x2][c0 + u]);
      *reinterpret_cast<uint4*>(dst + c0) = pk.v;
    }
  }
}

// ============ k_vote3: combine shifted g-planes -> votes -> histogram ============
__global__ __launch_bounds__(256) void k_vote3(const float* __restrict__ g,
                                               const float* __restrict__ a,
                                               const float* __restrict__ bb,
                                               int* __restrict__ count) {
  __shared__ int hist[TSZ];
  const int t = threadIdx.x;
  for (int i = t; i < TSZ; i += 256) hist[i] = 0;
  __syncthreads();
  const int pix = blockIdx.x * 256 + t;
  const int n = pix >> 12, y = (pix >> 6) & 63, x = pix & 63;
  float acc = 0.f;
#pragma unroll
  for (int tap = 0; tap < 9; ++tap) {
    const int dy = tap / 3 - 1, dx = tap % 3 - 1;
    const int yy = y + dy, xx = x + dx;
    if ((unsigned)yy < 64u && (unsigned)xx < 64u)
      acc += g[tap * 65536 + (n << 12) + (yy << 6) + xx];
  }
  {
    const float* av = a + 1152;
#pragma unroll
    for (int ky = 0; ky < 3; ++ky) {
      int yy = y + ky - 1;
      if ((unsigned)yy >= 64u) continue;
#pragma unroll
      for (int kx = 0; kx < 3; ++kx) {
        int xx = x + kx - 1;
        if ((unsigned)xx >= 64u) continue;
        acc += 0.5f * av[ky * 3 + kx];
      }
    }
  }
  int v = (int)floorf((acc + bb[0]) / RDIV);
  int r = v % TSZ; if (r < 0) r = -r;
  atomicAdd(&hist[r], 1);
  __syncthreads();
  for (int i = t; i < TSZ; i += 256) {
    int h = hist[i];
    if (h) atomicAdd(&count[i], h);
  }
}

// ============ hash pipeline (fp32-exact, proven) ============
__global__ __launch_bounds__(256) void k_norm(const float* __restrict__ k,
                                              unsigned* __restrict__ scaleBits) {
  int o = blockIdx.x;
  const float* row = k + (size_t)o * 1152;
  float s = 0.f;
  for (int j = threadIdx.x; j < 1152; j += 256) { float v = row[j]; s += v * v; }
  __shared__ float red[256];
  red[threadIdx.x] = s; __syncthreads();
  for (int st = 128; st; st >>= 1) {
    if (threadIdx.x < st) red[threadIdx.x] += red[threadIdx.x + st];
    __syncthreads();
  }
  if (threadIdx.x == 0) atomicMax(scaleBits, __float_as_uint(red[0]));
}

__global__ __launch_bounds__(256) void k_hash(const float* __restrict__ k,
                                              const float* __restrict__ a,
                                              const float* __restrict__ b,
                                              const unsigned* __restrict__ scaleBits,
                                              int* __restrict__ bucket) {
  int o = blockIdx.x;
  float scale = UCONST / sqrtf(__uint_as_float(scaleBits[0]));
  const float* row = k + (size_t)o * 1152;
  float dot = 0.f, p = 0.f;
  for (int j = threadIdx.x; j < 1152; j += 256) {
    float x = row[j] * scale;
    dot += x * a[j];
    p += x * x;
  }
  __shared__ float rd[256], rp[256];
  rd[threadIdx.x] = dot; rp[threadIdx.x] = p; __syncthreads();
  for (int st = 128; st; st >>= 1) {
    if (threadIdx.x < st) { rd[threadIdx.x] += rd[threadIdx.x + st]; rp[threadIdx.x] += rp[threadIdx.x + st]; }
    __syncthreads();
  }
  if (threadIdx.x == 0) {
    float acc = rd[0];
    float pw = rp[0];
    for (int i = 0; i < 9; i++) { acc += pw * a[1152 + i]; pw = pw * pw; }
    acc += b[0];
    float h = floorf(acc / RDIV);
    int hi = (int)h;
    int r = hi % TSZ; if (r < 0) r = -r;
    bucket[o] = r;
  }
}

__global__ __launch_bounds__(1024) void k_argmax(const int* __restrict__ count,
                                                 const int* __restrict__ bucket,
                                                 int* __restrict__ maskI,
                                                 float* __restrict__ tail) {
  __shared__ int sc[1024];
  __shared__ int si[1024];
  int t = threadIdx.x;
  sc[t] = count[t]; si[t] = t; __syncthreads();
  for (int st = 512; st; st >>= 1) {
    if (t < st) {
      int c2 = sc[t + st], i2 = si[t + st];
      if (c2 > sc[t] || (c2 == sc[t] && i2 < si[t])) { sc[t] = c2; si[t] = i2; }
    }
    __syncthreads();
  }
  int idx = si[0];
  if (t == 0) tail[0] = (float)idx;
  if (t < 256) {
    int m = (bucket[t] == idx) ? 1 : 0;
    maskI[t] = m;
    tail[1 + t] = (float)m;
  }
}

__global__ __launch_bounds__(256) void k_wprep(const float* __restrict__ w,
                                               const int* __restrict__ maskI,
                                               ushortT* __restrict__ wb) {
  const int o = blockIdx.x;
  const float m = maskI[o] ? 1.f : 0.f;
  const float* wr = w + (size_t)o * 1152;
  ushortT* dst = wb + (size_t)o * 1152;
  for (int j = threadIdx.x; j < 1152; j += 256) {
    int r = j >> 7, c = j & 127;
    dst[j] = bf16r(wr[c * 9 + r] * m);
  }
}

// ============ k_gemm3: M=65536, N=256, K=1152 ============
// BM=128 (2 rows), BN=256 (all o), BK=32. 512 thr = 8 waves (2M x 4N),
// per-wave 64x64. 3 LDS bufs x 24KB = 72KB -> 2 blocks/CU. Fragment-linear
// LDS (chunk*1KB + lane*16B): zero bank conflicts. Counted vmcnt(3) gate.
__global__ __launch_bounds__(512, 2) void k_gemm3(const ushortT* __restrict__ nb,
                                                  const ushortT* __restrict__ wb,
                                                  const char* __restrict__ zp,
                                                  float* __restrict__ out) {
  __shared__ __align__(16) char smem[3 * 24576];
  const int t = threadIdx.x, l = t & 63, w = t >> 6;
  const int mb = blockIdx.x;
  const int n = mb >> 5;
  const int y0 = (mb & 31) << 1;
  const int wm = w & 1, wn = w >> 1;
  const int lr = l & 15, lq = l >> 4;
  const char* nbN = (const char*)nb + (size_t)n * 1048576;

  // wave w stages chunks {3w, 3w+1, 3w+2}; c<8: A (16 pixels), else B (16 o-rows)
  int cA[3], yA[3], xA[3];
  const char* bPj[3];
#pragma unroll
  for (int j = 0; j < 3; ++j) {
    int c = w * 3 + j;
    cA[j] = c;
    int m = (c << 4) + lr;
    yA[j] = y0 + (m >> 6);
    xA[j] = m & 63;
    int orow = ((c - 8) << 4) + lr;
    bPj[j] = (const char*)wb + (size_t)orow * 2304 + (lq << 4);
  }

  auto stage = [&](int buf, int s) {
    const int tap = s >> 2;
    const int d3 = tap / 3;
    const int dy = d3 - 1, dx = tap - d3 * 3 - 1;
    const int cb = (s & 3) << 6;
    char* dstb = smem + buf * 24576;
#pragma unroll
    for (int j = 0; j < 3; ++j) {
      const char* src;
      if (cA[j] < 8) {
        int yy = yA[j] + dy, xx = xA[j] + dx;
        bool ok = ((unsigned)yy < 64u) && ((unsigned)xx < 64u);
        src = ok ? (nbN + (((yy << 6) + xx) << 8) + cb + (lq << 4))
                 : (zp + (lq << 4));
      } else {
        src = bPj[j] + (s << 6);
      }
      glds16(src, dstb + (cA[j] << 10));
    }
  };

  f32x4 acc[4][4] = {};

  stage(0, 0);
  stage(1, 1);
  asm volatile("s_waitcnt vmcnt(3)" ::: "memory");
  __builtin_amdgcn_s_barrier();

  for (int tt = 0; tt < 36; ++tt) {
    if (tt > 0) {
      if (tt < 35) { asm volatile("s_waitcnt vmcnt(3)" ::: "memory"); }
      else         { asm volatile("s_waitcnt vmcnt(0)" ::: "memory"); }
      __builtin_amdgcn_s_barrier();
    }
    if (tt + 2 < 36) stage((tt + 2) % 3, tt + 2);
    const char* bufb = smem + (tt % 3) * 24576;
    bf16x8 af[4], bv[4];
#pragma unroll
    for (int mi = 0; mi < 4; ++mi)
      af[mi] = *reinterpret_cast<const bf16x8*>(
          bufb + ((((wm << 2) + mi)) << 10) + (l << 4));
#pragma unroll
    for (int ni = 0; ni < 4; ++ni)
      bv[ni] = *reinterpret_cast<const bf16x8*>(
          bufb + 8192 + ((((wn << 2) + ni)) << 10) + (l << 4));
    __builtin_amdgcn_s_setprio(1);
#pragma unroll
    for (int mi = 0; mi < 4; ++mi)
#pragma unroll
      for (int ni = 0; ni < 4; ++ni)
        acc[mi][ni] = __builtin_amdgcn_mfma_f32_16x16x32_bf16(
            af[mi], bv[ni], acc[mi][ni], 0, 0, 0);
    __builtin_amdgcn_s_setprio(0);
  }

  // epilogue: lane -> col o = wn*64+ni*16+lr, row m = wm*64+mi*16+lq*4+reg
#pragma unroll
  for (int ni = 0; ni < 4; ++ni) {
    const int o = (wn << 6) + (ni << 4) + lr;
    float* op = out + ((size_t)((n << 8) + o) << 12) + ((y0 + wm) << 6);
#pragma unroll
    for (int mi = 0; mi < 4; ++mi)
      *reinterpret_cast<f32x4*>(op + (mi << 4) + (lq << 2)) = acc[mi][ni];
  }
}

// ============ MED-tier fused vote+cvt (round-4, proven) ============
__global__ __launch_bounds__(256) void k_votecvt(const float* __restrict__ in,
                                                 const float* __restrict__ a,
                                                 const float* __restrict__ bb,
                                                 int* __restrict__ count,
                                                 ushortT* __restrict__ nb) {
  __shared__ float sb[6][8][64];
  __shared__ int hist[TSZ];
  const int t = threadIdx.x;
  for (int i = t; i < TSZ; i += 256) hist[i] = 0;
  const int bid = blockIdx.x;
  const int n = bid >> 4, y0 = (bid & 15) << 2;
  const int x = t & 63, ry = t >> 6;
  const int yq = y0 + ry;
  float acc = 0.f;
  const float* base = in + (size_t)n * 524288;
  ushortT* nbrow = nb + (((size_t)(n * 64 + yq) << 6) + x) * 128;
  for (int cc = 0; cc < 16; ++cc) {
    __syncthreads();
#pragma unroll
    for (int k = 0; k < 12; ++k) {
      int i = k * 256 + t;
      int row = i >> 9;
      int c8 = (i >> 6) & 7;
      int xx = i & 63;
      int yy = y0 - 1 + row;
      float v = 0.f;
      if ((unsigned)yy < 64u) v = base[(size_t)(cc * 8 + c8) * 4096 + yy * 64 + xx];
      sb[row][c8][xx] = v;
    }
    __syncthreads();
#pragma unroll
    for (int c8 = 0; c8 < 8; ++c8) {
      const float* av = a + (cc * 8 + c8) * 9;
#pragma unroll
      for (int ky = 0; ky < 3; ++ky) {
        const float* rowp = sb[ry + ky][c8];
        float left  = (x >= 1)  ? rowp[x - 1] : 0.f;
        float mid   = rowp[x];
        float right = (x <= 62) ? rowp[x + 1] : 0.f;
        acc += left * av[ky * 3 + 0] + mid * av[ky * 3 + 1] + right * av[ky * 3 + 2];
      }
    }
    {
      union { ushortT us[8]; uint4 v; } pk;
#pragma unroll
      for (int c8 = 0; c8 < 8; ++c8) pk.us[c8] = bf16r(sb[ry + 1][c8][x]);
      *reinterpret_cast<uint4*>(nbrow + cc * 8) = pk.v;
    }
  }
  {
    const float* av = a + 1152;
#pragma unroll
    for (int ky = 0; ky < 3; ++ky) {
      int yy = yq + ky - 1;
      if ((unsigned)yy >= 64u) continue;
#pragma unroll
      for (int kx = 0; kx < 3; ++kx) {
        int xx = x + kx - 1;
        if ((unsigned)xx >= 64u) continue;
        acc += 0.5f * av[ky * 3 + kx];
      }
    }
  }
  int v = (int)floorf((acc + bb[0]) / RDIV);
  int r = v % TSZ; if (r < 0) r = -r;
  atomicAdd(&hist[r], 1);
  __syncthreads();
  for (int i = t; i < TSZ; i += 256) {
    int h = hist[i];
    if (h) atomicAdd(&count[i], h);
  }
}

// ============ SMALL-tier fallback (round-1, known-good) ============
__global__ __launch_bounds__(256) void k_conv(const float* __restrict__ in,
                                              const float* __restrict__ w,
                                              const int* __restrict__ maskI,
                                              float* __restrict__ out) {
  const int og = blockIdx.x, n = blockIdx.y, yt = blockIdx.z;
  const int tid = threadIdx.x;
  const int tx = tid & 63, trow = tid >> 6;
  const int y0 = yt * 4;
  const int oc0 = og * 4;
  const int m0 = maskI[oc0], m1 = maskI[oc0 + 1], m2 = maskI[oc0 + 2], m3 = maskI[oc0 + 3];
  float* op = out + ((size_t)(n * 256 + oc0)) * 4096 + (size_t)(y0 + trow) * 64 + tx;
  if (!(m0 | m1 | m2 | m3)) {
    op[0] = 0.f; op[4096] = 0.f; op[8192] = 0.f; op[12288] = 0.f;
    return;
  }
  __shared__ float tile[6 * 66];
  const float* base = in + (size_t)n * 128 * 4096;
  const float* wb = w + (size_t)oc0 * 1152;
  float a0 = 0.f, a1 = 0.f, a2 = 0.f, a3 = 0.f;
  for (int c = 0; c < 128; c++) {
    __syncthreads();
    for (int i = tid; i < 396; i += 256) {
      int r = i / 66, col = i - r * 66;
      int yy = y0 - 1 + r, xx = col - 1;
      float v = 0.f;
      if ((unsigned)yy < 64u && (unsigned)xx < 64u) v = base[(size_t)c * 4096 + yy * 64 + xx];
      tile[i] = v;
    }
    __syncthreads();
    const int ro = trow * 66 + tx;
    float t00 = tile[ro],        t01 = tile[ro + 1],   t02 = tile[ro + 2];
    float t10 = tile[ro + 66],   t11 = tile[ro + 67],  t12 = tile[ro + 68];
    float t20 = tile[ro + 132],  t21 = tile[ro + 133], t22 = tile[ro + 134];
    const float* wc = wb + c * 9;
    if (m0) { const float* q = wc;        a0 += t00*q[0]+t01*q[1]+t02*q[2]+t10*q[3]+t11*q[4]+t12*q[5]+t20*q[6]+t21*q[7]+t22*q[8]; }
    if (m1) { const float* q = wc + 1152; a1 += t00*q[0]+t01*q[1]+t02*q[2]+t10*q[3]+t11*q[4]+t12*q[5]+t20*q[6]+t21*q[7]+t22*q[8]; }
    if (m2) { const float* q = wc + 2304; a2 += t00*q[0]+t01*q[1]+t02*q[2]+t10*q[3]+t11*q[4]+t12*q[5]+t20*q[6]+t21*q[7]+t22*q[8]; }
    if (m3) { const float* q = wc + 3456; a3 += t00*q[0]+t01*q[1]+t02*q[2]+t10*q[3]+t11*q[4]+t12*q[5]+t20*q[6]+t21*q[7]+t22*q[8]; }
  }
  op[0]     = m0 ? a0 : 0.f;
  op[4096]  = m1 ? a1 : 0.f;
  op[8192]  = m2 ? a2 : 0.f;
  op[12288] = m3 ? a3 : 0.f;
}

extern "C" void kernel_launch(void* const* d_in, const int* in_sizes, int n_in,
                              void* d_out, int out_size, void* d_ws, size_t ws_size,
                              hipStream_t stream) {
  const float* in = (const float*)d_in[0];   // [16,128,64,64]
  const float* kw = (const float*)d_in[1];   // [256,128,3,3]
  const float* a  = (const float*)d_in[2];   // [1161]
  const float* b  = (const float*)d_in[3];   // [1]
  float* out = (float*)d_out;                // 16777216 + 1 + 256 floats

  char* ws = (char*)d_ws;
  const size_t NEED_BIG = 19732800ULL;
  const size_t NEED_MED = 17374720ULL;

  if (ws_size >= NEED_BIG) {
    // -------- new fast path --------
    ushortT* nb   = (ushortT*)(ws);                 // 16,777,216 B NHWC bf16
    ushortT* wb   = (ushortT*)(ws + 16777216);      // 589,824 B
    float* g      = (float*)(ws + 17367040);        // 2,359,296 B (9 planes)
    int* count    = (int*)(ws + 19726336);          // 4096
    unsigned* scB = (unsigned*)(ws + 19730432);     // 64
    char* zpage   = (ws + 19730496);                // 256
    int* bucket   = (int*)(ws + 19730752);          // 1024
    int* maskI    = (int*)(ws + 19731776);          // 1024

    hipMemsetAsync(ws + 19726336, 0, 4416, stream); // count+scB+zpage

    k_norm<<<256, 256, 0, stream>>>(kw, scB);
    k_hash<<<256, 256, 0, stream>>>(kw, a, b, scB, bucket);
    k_cvtg<<<1024, 256, 0, stream>>>(in, a, nb, g);
    k_vote3<<<256, 256, 0, stream>>>(g, a, b, count);
    k_argmax<<<1, 1024, 0, stream>>>(count, bucket, maskI, out + 16777216);
    k_wprep<<<256, 256, 0, stream>>>(kw, maskI, wb);
    k_gemm3<<<512, 512, 0, stream>>>(nb, wb, zpage, out);
  } else if (ws_size >= NEED_MED) {
    // -------- MED: round-4 vote path + new gemm --------
    ushortT* nb   = (ushortT*)(ws);
    ushortT* wb   = (ushortT*)(ws + 16777216);
    int* count    = (int*)(ws + 17367040);
    unsigned* scB = (unsigned*)(ws + 17371136);
    char* zpage   = (ws + 17371152);
    int* bucket   = (int*)(ws + 17371408);
    int* maskI    = (int*)(ws + 17372432);

    hipMemsetAsync(ws + 17367040, 0, 4368, stream);

    k_norm<<<256, 256, 0, stream>>>(kw, scB);
    k_hash<<<256, 256, 0, stream>>>(kw, a, b, scB, bucket);
    k_votecvt<<<256, 256, 0, stream>>>(in, a, b, count, nb);
    k_argmax<<<1, 1024, 0, stream>>>(count, bucket, maskI, out + 16777216);
    k_wprep<<<256, 256, 0, stream>>>(kw, maskI, wb);
    k_gemm3<<<512, 512, 0, stream>>>(nb, wb, zpage, out);
  } else {
    // -------- SMALL: direct conv path --------
    int* count    = (int*)(ws);
    unsigned* scB = (unsigned*)(ws + 4096);
    int* bucket   = (int*)(ws + 4160);
    int* maskI    = (int*)(ws + 5184);
    float* gdummy = nullptr; (void)gdummy;

    hipMemsetAsync(ws, 0, 4160, stream);
    k_norm<<<256, 256, 0, stream>>>(kw, scB);
    k_hash<<<256, 256, 0, stream>>>(kw, a, b, scB, bucket);
    // vote via votecvt is not possible (no nb space): reuse k_conv-path vote
    // (votecvt minus nb writes == original k_vote2 behavior) -> use k_votecvt
    // would write nb; instead use direct conv voting below.
    // Simple: reuse k_vote3 path impossible (no g). Use round-1 style vote:
    k_votecvt<<<256, 256, 0, stream>>>(in, a, b, count, (ushortT*)(ws + 8192)); // needs 16MB... guard:
    k_argmax<<<1, 1024, 0, stream>>>(count, bucket, maskI, out + 16777216);
    dim3 grid(64, 16, 16);
    k_conv<<<grid, 256, 0, stream>>>(in, kw, maskI, out);
  }
}

// Round 6
// 162.682 us; speedup vs baseline: 1.4458x; 1.0983x over previous
//
#include <hip/hip_runtime.h>
#include <cmath>
#include <cstdint>

#define TSZ 1024
#define RDIV 2.5f
#define UCONST 0.83f

typedef __bf16 bf16x8 __attribute__((ext_vector_type(8)));
typedef float f32x4 __attribute__((ext_vector_type(4)));
typedef unsigned short ushortT;

__device__ __forceinline__ ushortT bf16r(float f) {
  union { float f; unsigned u; } x; x.f = f;
  unsigned r = (x.u + 0x7FFFu + ((x.u >> 16) & 1u)) >> 16;
  return (ushortT)r;
}

__device__ __forceinline__ void glds16(const void* g, void* l) {
  __builtin_amdgcn_global_load_lds(
      (const __attribute__((address_space(1))) unsigned int*)(g),
      (__attribute__((address_space(3))) unsigned int*)(l), 16, 0, 0);
}

// ============ k_cvtg: NCHW fp32 -> (NHWC bf16) + per-pixel 9-tap dots ============
__global__ __launch_bounds__(256) void k_cvtg(const float* __restrict__ in,
                                              const float* __restrict__ a,
                                              ushortT* __restrict__ nb,
                                              float* __restrict__ g) {
  __shared__ float tile2[64][129];
  __shared__ float gpart[4][9][64];
  const int bid = blockIdx.x;
  const int n = bid >> 6, y = bid & 63;
  const int t = threadIdx.x;
  {
    const int chs = t >> 4, l16 = t & 15;
    const float* basep = in + ((size_t)(n * 128) << 12) + (y << 6) + (l16 << 2);
#pragma unroll
    for (int i = 0; i < 8; ++i) {
      int ch = (i << 4) + chs;
      f32x4 v = *reinterpret_cast<const f32x4*>(basep + ((size_t)ch << 12));
#pragma unroll
      for (int u = 0; u < 4; ++u) tile2[(l16 << 2) + u][ch] = v[u];
    }
  }
  __syncthreads();
  {
    const int part = __builtin_amdgcn_readfirstlane(t >> 6);
    const int x = t & 63;
    float gacc[9];
#pragma unroll
    for (int tap = 0; tap < 9; ++tap) gacc[tap] = 0.f;
    const int c0 = part << 5;
#pragma unroll
    for (int i = 0; i < 32; ++i) {
      float v = tile2[x][c0 + i];
      const float* ap = a + (c0 + i) * 9;
#pragma unroll
      for (int tap = 0; tap < 9; ++tap) gacc[tap] += v * ap[tap];
    }
#pragma unroll
    for (int tap = 0; tap < 9; ++tap) gpart[part][tap][x] = gacc[tap];
  }
  __syncthreads();
  if (t < 64) {
    const int x = t;
#pragma unroll
    for (int tap = 0; tap < 9; ++tap) {
      float s = gpart[0][tap][x] + gpart[1][tap][x] + gpart[2][tap][x] + gpart[3][tap][x];
      g[tap * 65536 + (n << 12) + (y << 6) + x] = s;
    }
  }
  {
    const int x2 = t >> 2;
    ushortT* dst = nb + (((size_t)((n << 6) + y) << 6) + x2) * 128;
#pragma unroll
    for (int j = 0; j < 4; ++j) {
      int c0 = ((t & 3) << 3) + (j << 5);
      union { ushortT us[8]; uint4 v; } pk;
#pragma unroll
      for (int u = 0; u < 8; ++u) pk.us[u] = bf16r(tile2[x2][c0 + u]);
      *reinterpret_cast<uint4*>(dst + c0) = pk.v;
    }
  }
}

// ============ k_vote3: combine shifted g-planes -> votes -> histogram ============
__global__ __launch_bounds__(256) void k_vote3(const float* __restrict__ g,
                                               const float* __restrict__ a,
                                               const float* __restrict__ bb,
                                               int* __restrict__ count) {
  __shared__ int hist[TSZ];
  const int t = threadIdx.x;
  for (int i = t; i < TSZ; i += 256) hist[i] = 0;
  __syncthreads();
  const int pix = blockIdx.x * 256 + t;
  const int n = pix >> 12, y = (pix >> 6) & 63, x = pix & 63;
  float acc = 0.f;
#pragma unroll
  for (int tap = 0; tap < 9; ++tap) {
    const int dy = tap / 3 - 1, dx = tap % 3 - 1;
    const int yy = y + dy, xx = x + dx;
    if ((unsigned)yy < 64u && (unsigned)xx < 64u)
      acc += g[tap * 65536 + (n << 12) + (yy << 6) + xx];
  }
  {
    const float* av = a + 1152;
#pragma unroll
    for (int ky = 0; ky < 3; ++ky) {
      int yy = y + ky - 1;
      if ((unsigned)yy >= 64u) continue;
#pragma unroll
      for (int kx = 0; kx < 3; ++kx) {
        int xx = x + kx - 1;
        if ((unsigned)xx >= 64u) continue;
        acc += 0.5f * av[ky * 3 + kx];
      }
    }
  }
  int v = (int)floorf((acc + bb[0]) / RDIV);
  int r = v % TSZ; if (r < 0) r = -r;
  atomicAdd(&hist[r], 1);
  __syncthreads();
  for (int i = t; i < TSZ; i += 256) {
    int h = hist[i];
    if (h) atomicAdd(&count[i], h);
  }
}

// ============ hash pipeline (fp32-exact, proven) ============
__global__ __launch_bounds__(256) void k_norm(const float* __restrict__ k,
                                              unsigned* __restrict__ scaleBits) {
  int o = blockIdx.x;
  const float* row = k + (size_t)o * 1152;
  float s = 0.f;
  for (int j = threadIdx.x; j < 1152; j += 256) { float v = row[j]; s += v * v; }
  __shared__ float red[256];
  red[threadIdx.x] = s; __syncthreads();
  for (int st = 128; st; st >>= 1) {
    if (threadIdx.x < st) red[threadIdx.x] += red[threadIdx.x + st];
    __syncthreads();
  }
  if (threadIdx.x == 0) atomicMax(scaleBits, __float_as_uint(red[0]));
}

__global__ __launch_bounds__(256) void k_hash(const float* __restrict__ k,
                                              const float* __restrict__ a,
                                              const float* __restrict__ b,
                                              const unsigned* __restrict__ scaleBits,
                                              int* __restrict__ bucket) {
  int o = blockIdx.x;
  float scale = UCONST / sqrtf(__uint_as_float(scaleBits[0]));
  const float* row = k + (size_t)o * 1152;
  float dot = 0.f, p = 0.f;
  for (int j = threadIdx.x; j < 1152; j += 256) {
    float x = row[j] * scale;
    dot += x * a[j];
    p += x * x;
  }
  __shared__ float rd[256], rp[256];
  rd[threadIdx.x] = dot; rp[threadIdx.x] = p; __syncthreads();
  for (int st = 128; st; st >>= 1) {
    if (threadIdx.x < st) { rd[threadIdx.x] += rd[threadIdx.x + st]; rp[threadIdx.x] += rp[threadIdx.x + st]; }
    __syncthreads();
  }
  if (threadIdx.x == 0) {
    float acc = rd[0];
    float pw = rp[0];
    for (int i = 0; i < 9; i++) { acc += pw * a[1152 + i]; pw = pw * pw; }
    acc += b[0];
    float h = floorf(acc / RDIV);
    int hi = (int)h;
    int r = hi % TSZ; if (r < 0) r = -r;
    bucket[o] = r;
  }
}

// ============ merged argmax + mask + weight prep (BIG path) ============
// grid 256 blocks: each block redundantly reduces count[1024] -> idx,
// then preps its own masked bf16 weight row; writes tail mask element.
__global__ __launch_bounds__(256) void k_wprep2(const int* __restrict__ count,
                                                const int* __restrict__ bucket,
                                                const float* __restrict__ w,
                                                ushortT* __restrict__ wb,
                                                float* __restrict__ tail) {
  __shared__ int sc[256];
  __shared__ int si[256];
  const int t = threadIdx.x;
  // thread-local scan of 4 strided entries (>, so lowest index wins ties)
  int bc = count[t], bi = t;
#pragma unroll
  for (int j = 1; j < 4; ++j) {
    int i2 = t + j * 256;
    int c2 = count[i2];
    if (c2 > bc) { bc = c2; bi = i2; }
  }
  sc[t] = bc; si[t] = bi; __syncthreads();
  for (int st = 128; st; st >>= 1) {
    if (t < st) {
      int c2 = sc[t + st], i2 = si[t + st];
      if (c2 > sc[t] || (c2 == sc[t] && i2 < si[t])) { sc[t] = c2; si[t] = i2; }
    }
    __syncthreads();
  }
  const int idx = si[0];
  const int o = blockIdx.x;
  const int m = (bucket[o] == idx) ? 1 : 0;
  if (t == 0) {
    if (o == 0) tail[0] = (float)idx;
    tail[1 + o] = (float)m;
  }
  const float mf = m ? 1.f : 0.f;
  const float* wr = w + (size_t)o * 1152;
  ushortT* dst = wb + (size_t)o * 1152;
  for (int j = t; j < 1152; j += 256) {
    int r = j >> 7, c = j & 127;
    dst[j] = bf16r(wr[c * 9 + r] * mf);
  }
}

// ============ k_gemm3r: M=65536, N=256, K=1152 ============
// BM=256 (4 rows), BN=256, BK=32. 512 thr = 8 waves (2M x 4N), wave tile
// 128x64 (acc 8x4 f32x4 = 128 VGPR). 3 LDS bufs x 32KB = 96KB, 1 block/CU.
// Fragment-linear LDS (chunk*1KB + lane*16B): zero bank conflicts.
// Counted vmcnt(4) gate, 2-deep prefetch, one barrier per K-tile.
__global__ __launch_bounds__(512, 2) void k_gemm3r(const ushortT* __restrict__ nb,
                                                   const ushortT* __restrict__ wb,
                                                   const char* __restrict__ zp,
                                                   float* __restrict__ out) {
  __shared__ __align__(16) char smem[3 * 32768];
  const int t = threadIdx.x, l = t & 63, w = t >> 6;
  const int mb = blockIdx.x;               // 256 = 16 n * 16 ygroups
  const int n = mb >> 4;
  const int y0 = (mb & 15) << 2;
  const int wm = w & 1, wn = w >> 1;
  const int lr = l & 15, lq = l >> 4;
  const char* nbN = (const char*)nb + (size_t)n * 1048576;

  // wave w stages chunks {4w..4w+3}; c<16: A frag c (16 pixels), else B frag c-16
  int cC[4], yA[4], xA[4];
  const char* bPj[4];
#pragma unroll
  for (int j = 0; j < 4; ++j) {
    int c = (w << 2) + j;
    cC[j] = c;
    int m = (c << 4) + lr;                 // pixel index in [0,256)
    yA[j] = y0 + (m >> 6);
    xA[j] = m & 63;
    int orow = ((c - 16) << 4) + lr;
    bPj[j] = (const char*)wb + (size_t)orow * 2304 + (lq << 4);
  }

  auto stage = [&](int buf, int s) {
    const int tap = s >> 2;
    const int d3 = tap * 0x5556 >> 16;     // tap/3 for tap<9
    const int dy = d3 - 1, dx = tap - d3 * 3 - 1;
    const int cb = (s & 3) << 6;
    char* dstb = smem + buf * 32768;
#pragma unroll
    for (int j = 0; j < 4; ++j) {
      const char* src;
      if (cC[j] < 16) {
        int yy = yA[j] + dy, xx = xA[j] + dx;
        bool ok = ((unsigned)yy < 64u) && ((unsigned)xx < 64u);
        src = ok ? (nbN + (((yy << 6) + xx) << 8) + cb + (lq << 4))
                 : (zp + (lq << 4));
      } else {
        src = bPj[j] + (s << 6);
      }
      glds16(src, dstb + (cC[j] << 10));
    }
  };

  f32x4 acc[8][4] = {};

  stage(0, 0);
  stage(1, 1);
  asm volatile("s_waitcnt vmcnt(4)" ::: "memory");
  __builtin_amdgcn_s_barrier();

  for (int tt = 0; tt < 36; ++tt) {
    if (tt > 0) {
      if (tt < 35) { asm volatile("s_waitcnt vmcnt(4)" ::: "memory"); }
      else         { asm volatile("s_waitcnt vmcnt(0)" ::: "memory"); }
      __builtin_amdgcn_s_barrier();
    }
    if (tt + 2 < 36) stage((tt + 2) % 3, tt + 2);
    const char* bufb = smem + (tt % 3) * 32768;
    bf16x8 af[8], bv[4];
#pragma unroll
    for (int mi = 0; mi < 8; ++mi)
      af[mi] = *reinterpret_cast<const bf16x8*>(
          bufb + (((wm << 3) + mi) << 10) + (l << 4));
#pragma unroll
    for (int ni = 0; ni < 4; ++ni)
      bv[ni] = *reinterpret_cast<const bf16x8*>(
          bufb + 16384 + (((wn << 2) + ni) << 10) + (l << 4));
    __builtin_amdgcn_s_setprio(1);
#pragma unroll
    for (int mi = 0; mi < 8; ++mi)
#pragma unroll
      for (int ni = 0; ni < 4; ++ni)
        acc[mi][ni] = __builtin_amdgcn_mfma_f32_16x16x32_bf16(
            af[mi], bv[ni], acc[mi][ni], 0, 0, 0);
    __builtin_amdgcn_s_setprio(0);
  }

  // epilogue: col o = wn*64+ni*16+lr, row m = wm*128+mi*16+lq*4+reg (contig x)
  const int pos0 = (mb & 15) << 8;
#pragma unroll
  for (int ni = 0; ni < 4; ++ni) {
    const int o = (wn << 6) + (ni << 4) + lr;
    float* op = out + ((size_t)((n << 8) + o) << 12) + pos0 + (wm << 7) + (lq << 2);
#pragma unroll
    for (int mi = 0; mi < 8; ++mi)
      *reinterpret_cast<f32x4*>(op + (mi << 4)) = acc[mi][ni];
  }
}

// ============ SMALL-tier fallback kernels (known-good) ============
__global__ __launch_bounds__(256) void k_vote2(const float* __restrict__ in,
                                               const float* __restrict__ a,
                                               const float* __restrict__ bb,
                                               int* __restrict__ count) {
  __shared__ float sb[6][8][64];
  __shared__ int hist[TSZ];
  const int t = threadIdx.x;
  for (int i = t; i < TSZ; i += 256) hist[i] = 0;
  const int bid = blockIdx.x;
  const int n = bid >> 4, y0 = (bid & 15) << 2;
  const int x = t & 63, ry = t >> 6;
  const int yq = y0 + ry;
  float acc = 0.f;
  const float* base = in + (size_t)n * 524288;
  for (int cc = 0; cc < 16; ++cc) {
    __syncthreads();
#pragma unroll
    for (int k = 0; k < 12; ++k) {
      int i = k * 256 + t;
      int row = i >> 9;
      int c8 = (i >> 6) & 7;
      int xx = i & 63;
      int yy = y0 - 1 + row;
      float v = 0.f;
      if ((unsigned)yy < 64u) v = base[(size_t)(cc * 8 + c8) * 4096 + yy * 64 + xx];
      sb[row][c8][xx] = v;
    }
    __syncthreads();
#pragma unroll
    for (int c8 = 0; c8 < 8; ++c8) {
      const float* av = a + (cc * 8 + c8) * 9;
#pragma unroll
      for (int ky = 0; ky < 3; ++ky) {
        const float* rowp = sb[ry + ky][c8];
        float left  = (x >= 1)  ? rowp[x - 1] : 0.f;
        float mid   = rowp[x];
        float right = (x <= 62) ? rowp[x + 1] : 0.f;
        acc += left * av[ky * 3 + 0] + mid * av[ky * 3 + 1] + right * av[ky * 3 + 2];
      }
    }
  }
  {
    const float* av = a + 1152;
#pragma unroll
    for (int ky = 0; ky < 3; ++ky) {
      int yy = yq + ky - 1;
      if ((unsigned)yy >= 64u) continue;
#pragma unroll
      for (int kx = 0; kx < 3; ++kx) {
        int xx = x + kx - 1;
        if ((unsigned)xx >= 64u) continue;
        acc += 0.5f * av[ky * 3 + kx];
      }
    }
  }
  int v = (int)floorf((acc + bb[0]) / RDIV);
  int r = v % TSZ; if (r < 0) r = -r;
  atomicAdd(&hist[r], 1);
  __syncthreads();
  for (int i = t; i < TSZ; i += 256) {
    int h = hist[i];
    if (h) atomicAdd(&count[i], h);
  }
}

__global__ __launch_bounds__(1024) void k_argmax(const int* __restrict__ count,
                                                 const int* __restrict__ bucket,
                                                 int* __restrict__ maskI,
                                                 float* __restrict__ tail) {
  __shared__ int sc[1024];
  __shared__ int si[1024];
  int t = threadIdx.x;
  sc[t] = count[t]; si[t] = t; __syncthreads();
  for (int st = 512; st; st >>= 1) {
    if (t < st) {
      int c2 = sc[t + st], i2 = si[t + st];
      if (c2 > sc[t] || (c2 == sc[t] && i2 < si[t])) { sc[t] = c2; si[t] = i2; }
    }
    __syncthreads();
  }
  int idx = si[0];
  if (t == 0) tail[0] = (float)idx;
  if (t < 256) {
    int m = (bucket[t] == idx) ? 1 : 0;
    maskI[t] = m;
    tail[1 + t] = (float)m;
  }
}

__global__ __launch_bounds__(256) void k_conv(const float* __restrict__ in,
                                              const float* __restrict__ w,
                                              const int* __restrict__ maskI,
                                              float* __restrict__ out) {
  const int og = blockIdx.x, n = blockIdx.y, yt = blockIdx.z;
  const int tid = threadIdx.x;
  const int tx = tid & 63, trow = tid >> 6;
  const int y0 = yt * 4;
  const int oc0 = og * 4;
  const int m0 = maskI[oc0], m1 = maskI[oc0 + 1], m2 = maskI[oc0 + 2], m3 = maskI[oc0 + 3];
  float* op = out + ((size_t)(n * 256 + oc0)) * 4096 + (size_t)(y0 + trow) * 64 + tx;
  if (!(m0 | m1 | m2 | m3)) {
    op[0] = 0.f; op[4096] = 0.f; op[8192] = 0.f; op[12288] = 0.f;
    return;
  }
  __shared__ float tile[6 * 66];
  const float* base = in + (size_t)n * 128 * 4096;
  const float* wb = w + (size_t)oc0 * 1152;
  float a0 = 0.f, a1 = 0.f, a2 = 0.f, a3 = 0.f;
  for (int c = 0; c < 128; c++) {
    __syncthreads();
    for (int i = tid; i < 396; i += 256) {
      int r = i / 66, col = i - r * 66;
      int yy = y0 - 1 + r, xx = col - 1;
      float v = 0.f;
      if ((unsigned)yy < 64u && (unsigned)xx < 64u) v = base[(size_t)c * 4096 + yy * 64 + xx];
      tile[i] = v;
    }
    __syncthreads();
    const int ro = trow * 66 + tx;
    float t00 = tile[ro],        t01 = tile[ro + 1],   t02 = tile[ro + 2];
    float t10 = tile[ro + 66],   t11 = tile[ro + 67],  t12 = tile[ro + 68];
    float t20 = tile[ro + 132],  t21 = tile[ro + 133], t22 = tile[ro + 134];
    const float* wc = wb + c * 9;
    if (m0) { const float* q = wc;        a0 += t00*q[0]+t01*q[1]+t02*q[2]+t10*q[3]+t11*q[4]+t12*q[5]+t20*q[6]+t21*q[7]+t22*q[8]; }
    if (m1) { const float* q = wc + 1152; a1 += t00*q[0]+t01*q[1]+t02*q[2]+t10*q[3]+t11*q[4]+t12*q[5]+t20*q[6]+t21*q[7]+t22*q[8]; }
    if (m2) { const float* q = wc + 2304; a2 += t00*q[0]+t01*q[1]+t02*q[2]+t10*q[3]+t11*q[4]+t12*q[5]+t20*q[6]+t21*q[7]+t22*q[8]; }
    if (m3) { const float* q = wc + 3456; a3 += t00*q[0]+t01*q[1]+t02*q[2]+t10*q[3]+t11*q[4]+t12*q[5]+t20*q[6]+t21*q[7]+t22*q[8]; }
  }
  op[0]     = m0 ? a0 : 0.f;
  op[4096]  = m1 ? a1 : 0.f;
  op[8192]  = m2 ? a2 : 0.f;
  op[12288] = m3 ? a3 : 0.f;
}

extern "C" void kernel_launch(void* const* d_in, const int* in_sizes, int n_in,
                              void* d_out, int out_size, void* d_ws, size_t ws_size,
                              hipStream_t stream) {
  const float* in = (const float*)d_in[0];   // [16,128,64,64]
  const float* kw = (const float*)d_in[1];   // [256,128,3,3]
  const float* a  = (const float*)d_in[2];   // [1161]
  const float* b  = (const float*)d_in[3];   // [1]
  float* out = (float*)d_out;                // 16777216 + 1 + 256 floats

  char* ws = (char*)d_ws;
  const size_t NEED_BIG = 19731776ULL;

  if (ws_size >= NEED_BIG) {
    // -------- fast path --------
    ushortT* nb   = (ushortT*)(ws);                 // 16,777,216 B NHWC bf16
    ushortT* wb   = (ushortT*)(ws + 16777216);      // 589,824 B
    float* g      = (float*)(ws + 17367040);        // 2,359,296 B (9 planes)
    int* count    = (int*)(ws + 19726336);          // 4096
    unsigned* scB = (unsigned*)(ws + 19730432);     // 64
    char* zpage   = (ws + 19730496);                // 256
    int* bucket   = (int*)(ws + 19730752);          // 1024

    hipMemsetAsync(ws + 19726336, 0, 4416, stream); // count + scB + zpage

    k_norm<<<256, 256, 0, stream>>>(kw, scB);
    k_hash<<<256, 256, 0, stream>>>(kw, a, b, scB, bucket);
    k_cvtg<<<1024, 256, 0, stream>>>(in, a, nb, g);
    k_vote3<<<256, 256, 0, stream>>>(g, a, b, count);
    k_wprep2<<<256, 256, 0, stream>>>(count, bucket, kw, wb, out + 16777216);
    k_gemm3r<<<256, 512, 0, stream>>>(nb, wb, zpage, out);
  } else {
    // -------- fallback: direct conv path --------
    int* count    = (int*)(ws);                     // 4096
    unsigned* scB = (unsigned*)(ws + 4096);         // 64
    int* bucket   = (int*)(ws + 4160);              // 1024
    int* maskI    = (int*)(ws + 5184);              // 1024

    hipMemsetAsync(ws, 0, 4160, stream);
    k_norm<<<256, 256, 0, stream>>>(kw, scB);
    k_hash<<<256, 256, 0, stream>>>(kw, a, b, scB, bucket);
    k_vote2<<<256, 256, 0, stream>>>(in, a, b, count);
    k_argmax<<<1, 1024, 0, stream>>>(count, bucket, maskI, out + 16777216);
    dim3 grid(64, 16, 16);
    k_conv<<<grid, 256, 0, stream>>>(in, kw, maskI, out);
  }
}